// Round 1
// 872.614 us; speedup vs baseline: 1.0060x; 1.0060x over previous
//
#include <hip/hip_runtime.h>

#define N_NODES 50000
#define N_EDGES 1600000
#define D_NODE  256
#define D_EDGE  64
#define H       128
#define D_OUT   256

#define NPAD    50176   // 196*256, padded node count for scan

typedef __attribute__((ext_vector_type(8))) short bf16x8;
typedef __attribute__((ext_vector_type(4))) float f32x4;
typedef __attribute__((ext_vector_type(4))) unsigned short u16x4;

__device__ __forceinline__ float bf2f(unsigned short u) {
    union { unsigned int i; float f; } v; v.i = ((unsigned int)u) << 16; return v.f;
}
__device__ __forceinline__ unsigned short f2bf(float f) {
    union { float f; unsigned int i; } v; v.f = f;
    unsigned int r = v.i + 0x7FFFu + ((v.i >> 16) & 1u);
    return (unsigned short)(r >> 16);
}

// ---------- K0: convert fp32 weights to bf16 tables ----------
__global__ __launch_bounds__(256) void cvt_kernel(
        const float* __restrict__ Wn, const float* __restrict__ We,
        const float* __restrict__ Wr,
        unsigned short* __restrict__ Wn_b, unsigned short* __restrict__ We_b,
        unsigned short* __restrict__ Wr_b) {
    int b = blockIdx.x;
    const float* s; unsigned short* d; int base;
    if (b < 32)      { s = Wn; d = Wn_b; base = b * 1024; }
    else if (b < 40) { s = We; d = We_b; base = (b - 32) * 1024; }
    else             { s = Wr; d = Wr_b; base = (b - 40) * 1024; }
    int i = base + threadIdx.x * 4;
    f32x4 v = *(const f32x4*)(s + i);
    u16x4 o;
    #pragma unroll
    for (int j = 0; j < 4; ++j) o[j] = f2bf(v[j]);
    *(u16x4*)(d + i) = o;
}

// ---------- K1: hn = x @ Wn^T + bn -> bf16 [N, 128] ----------
__global__ __launch_bounds__(64) void hn_kernel(
        const float* __restrict__ x,
        const unsigned short* __restrict__ Wn_b,
        const float* __restrict__ bn,
        unsigned short* __restrict__ hn) {
    const int lane = threadIdx.x & 63;
    const int m = lane & 15, q = lane >> 4;
    const int n0 = blockIdx.x * 16;

    f32x4 acc[8];
    #pragma unroll
    for (int t = 0; t < 8; ++t)
        #pragma unroll
        for (int r = 0; r < 4; ++r) acc[t][r] = 0.0f;

    const float* xrow = x + (size_t)(n0 + m) * D_NODE + q * 8;
    #pragma unroll
    for (int kk = 0; kk < 8; ++kk) {
        f32x4 a0 = __builtin_nontemporal_load((const f32x4*)(xrow + kk * 32));
        f32x4 a1 = __builtin_nontemporal_load((const f32x4*)(xrow + kk * 32 + 4));
        bf16x8 a;
        #pragma unroll
        for (int j = 0; j < 4; ++j) {
            a[j]     = (short)f2bf(a0[j]);
            a[4 + j] = (short)f2bf(a1[j]);
        }
        #pragma unroll
        for (int t = 0; t < 8; ++t) {
            bf16x8 b = *(const bf16x8*)(Wn_b + (size_t)(t * 16 + m) * D_NODE + kk * 32 + q * 8);
            acc[t] = __builtin_amdgcn_mfma_f32_16x16x32_bf16(a, b, acc[t], 0, 0, 0);
        }
    }
    #pragma unroll
    for (int t = 0; t < 8; ++t) {
        int o = t * 16 + m;
        float bv = bn[o];
        #pragma unroll
        for (int r = 0; r < 4; ++r) {
            int node = n0 + q * 4 + r;
            hn[(size_t)node * H + o] = f2bf(acc[t][r] + bv);
        }
    }
}

// ---------- K2a: histogram cnt[dst]++ ----------
__global__ __launch_bounds__(256) void hist_kernel(
        const int* __restrict__ dst, unsigned int* __restrict__ cnt) {
    int e = blockIdx.x * 256 + threadIdx.x;
    atomicAdd(&cnt[dst[e]], 1u);
}

// shfl-based inclusive scan across a 256-thread block; returns inclusive, sets total.
__device__ __forceinline__ unsigned int block_scan_incl(unsigned int v, unsigned int* wtot) {
    const int lane = threadIdx.x & 63;
    const int wid = threadIdx.x >> 6;
    unsigned int x = v;
    #pragma unroll
    for (int off = 1; off < 64; off <<= 1) {
        unsigned int y = __shfl_up(x, off, 64);
        if (lane >= off) x += y;
    }
    if (lane == 63) wtot[wid] = x;
    __syncthreads();
    unsigned int wof = 0;
    #pragma unroll
    for (int w = 0; w < 4; ++w) if (w < wid) wof += wtot[w];
    return x + wof;
}

// ---------- K2b: per-block scan ----------
__global__ __launch_bounds__(256) void scan1_kernel(
        const unsigned int* __restrict__ cnt,
        unsigned int* __restrict__ partial,   // exclusive within block
        unsigned int* __restrict__ blocksum) {
    __shared__ unsigned int wtot[4];
    int i = blockIdx.x * 256 + threadIdx.x;
    unsigned int v = cnt[i];
    unsigned int inc = block_scan_incl(v, wtot);
    partial[i] = inc - v;
    if (threadIdx.x == 255) blocksum[blockIdx.x] = inc;
}

// ---------- K2c: scan the 196 block sums (padded to 256) ----------
__global__ __launch_bounds__(256) void scan2_kernel(
        const unsigned int* __restrict__ blocksum,
        unsigned int* __restrict__ blockoff) {
    __shared__ unsigned int wtot[4];
    unsigned int v = blocksum[threadIdx.x];
    unsigned int inc = block_scan_incl(v, wtot);
    blockoff[threadIdx.x] = inc - v;   // exclusive
}

// ---------- K2d: scatter edge ids into dst-bins ----------
// atomics run directly on partial[]; global position = partial-atomic + blockoff.
// After this kernel partial[n] == within-block-exclusive + cnt[n].
__global__ __launch_bounds__(256) void scatter_kernel(
        const int* __restrict__ src, const int* __restrict__ dst,
        unsigned int* __restrict__ partial,
        const unsigned int* __restrict__ blockoff,
        unsigned long long* __restrict__ eid_src) {
    int e = blockIdx.x * 256 + threadIdx.x;
    int d = dst[e];
    unsigned int s = (unsigned int)src[e];
    unsigned int pos = atomicAdd(&partial[d], 1u) + blockoff[d >> 8];
    eid_src[pos] = ((unsigned long long)s << 32) | (unsigned int)e;
}

// ---------- K3: fused aggregation + mean_state + out GEMM, 16 nodes/block ----------
__global__ __launch_bounds__(256) void fused_kernel(
        const unsigned long long* __restrict__ eid_src,
        const unsigned int* __restrict__ partial,   // post-scatter
        const unsigned int* __restrict__ blockoff,
        const unsigned int* __restrict__ cnt,
        const float* __restrict__ ez,
        const unsigned int* __restrict__ hn32,
        const unsigned short* __restrict__ We_b,
        const float* __restrict__ be,
        const unsigned short* __restrict__ Wr_b,
        const float* __restrict__ br,
        float* __restrict__ out) {
    __shared__ __align__(16) unsigned short ms[16][264];
    __shared__ __align__(16) float seL[16][68];   // +4 pad: 2-way banks on MFMA a-read
    __shared__ float rden[16];
    __shared__ float degf[16];

    const int t = threadIdx.x;
    const int n0 = blockIdx.x * 16;
    const int wid = t >> 6;
    const int lane = t & 63;

    if (t < 16) {
        unsigned int dg = cnt[n0 + t];
        degf[t] = (float)dg;
        rden[t] = 1.0f / (1.0f + (float)dg);
    }

    // ---- phase 1: aggregation. wave wid owns nodes wid*4 .. wid*4+3 ----
    for (int nl = 0; nl < 4; ++nl) {
        const int row = wid * 4 + nl;
        const int n = n0 + row;
        const unsigned int c = cnt[n];
        const unsigned int end = partial[n] + blockoff[n >> 8];
        const unsigned int beg = end - c;
        float se = 0.0f, sn0 = 0.0f, sn1 = 0.0f;

        for (unsigned int base = beg; base < end; base += 64) {
            int mcnt = (int)(end - base); if (mcnt > 64) mcnt = 64;
            unsigned long long ent = (lane < mcnt)
                ? __builtin_nontemporal_load(eid_src + base + lane) : 0ULL;
            unsigned int elo = (unsigned int)ent;
            unsigned int shi = (unsigned int)(ent >> 32);

            int j = 0;
            for (; j + 8 <= mcnt; j += 8) {
                unsigned int e[8], s[8];
                #pragma unroll
                for (int u = 0; u < 8; ++u) {
                    e[u] = __shfl(elo, j + u, 64);
                    s[u] = __shfl(shi, j + u, 64);
                }
                float a[8]; unsigned int h[8];
                #pragma unroll
                for (int u = 0; u < 8; ++u)
                    a[u] = __builtin_nontemporal_load(ez + (size_t)e[u] * D_EDGE + lane);
                #pragma unroll
                for (int u = 0; u < 8; ++u)
                    h[u] = hn32[(size_t)s[u] * 64 + lane];
                #pragma unroll
                for (int u = 0; u < 8; ++u) {
                    se += a[u];
                    union { unsigned int ui; float f; } lo, hi;
                    lo.ui = h[u] << 16; hi.ui = h[u] & 0xffff0000u;
                    sn0 += lo.f; sn1 += hi.f;
                }
            }
            for (; j < mcnt; ++j) {
                unsigned int e0 = __shfl(elo, j, 64), s0 = __shfl(shi, j, 64);
                float a0 = __builtin_nontemporal_load(ez + (size_t)e0 * D_EDGE + lane);
                unsigned int h0 = hn32[(size_t)s0 * 64 + lane];
                se += a0;
                union { unsigned int ui; float f; } lo, hi;
                lo.ui = h0 << 16; hi.ui = h0 & 0xffff0000u;
                sn0 += lo.f; sn1 += hi.f;
            }
        }

        seL[row][lane] = se;
        // node half: ms[row, 2l..2l+1] = (hn + sumN) / (deg+1)
        unsigned int hv = hn32[(size_t)n * 64 + lane];
        float rd = 1.0f / (1.0f + (float)c);
        union { unsigned int ui; float f; } lo, hi;
        lo.ui = hv << 16; hi.ui = hv & 0xffff0000u;
        unsigned int p = ((unsigned int)f2bf((hi.f + sn1) * rd) << 16)
                       |  (unsigned int)f2bf((lo.f + sn0) * rd);
        *(unsigned int*)&ms[row][2 * lane] = p;
    }
    __syncthreads();

    // ---- phase 2: edge half: ms[:,128:256] = (sumEZ @ We^T + deg*be) * rden ----
    {
        const int m = lane & 15, q = lane >> 4;
        f32x4 acc[2];
        #pragma unroll
        for (int i = 0; i < 2; ++i)
            #pragma unroll
            for (int r = 0; r < 4; ++r) acc[i][r] = 0.0f;

        #pragma unroll
        for (int kk = 0; kk < 2; ++kk) {
            const float* ap = &seL[m][kk * 32 + q * 8];
            f32x4 a0 = *(const f32x4*)ap;
            f32x4 a1 = *(const f32x4*)(ap + 4);
            bf16x8 a;
            #pragma unroll
            for (int j = 0; j < 4; ++j) {
                a[j]     = (short)f2bf(a0[j]);
                a[4 + j] = (short)f2bf(a1[j]);
            }
            #pragma unroll
            for (int i = 0; i < 2; ++i) {
                int o0 = (wid + 4 * i) * 16;
                bf16x8 b = *(const bf16x8*)(We_b + (size_t)(o0 + m) * D_EDGE + kk * 32 + q * 8);
                acc[i] = __builtin_amdgcn_mfma_f32_16x16x32_bf16(a, b, acc[i], 0, 0, 0);
            }
        }
        #pragma unroll
        for (int i = 0; i < 2; ++i) {
            int o = (wid + 4 * i) * 16 + m;
            float bev = be[o];
            #pragma unroll
            for (int r = 0; r < 4; ++r) {
                int nl = q * 4 + r;
                float val = (acc[i][r] + degf[nl] * bev) * rden[nl];
                ms[nl][128 + o] = f2bf(val);
            }
        }
    }
    __syncthreads();

    // ---- phase 3: out = ms @ Wr^T + br ; zero rows with deg==0 ----
    {
        const int m = lane & 15, q = lane >> 4;
        f32x4 acc[4];
        #pragma unroll
        for (int i = 0; i < 4; ++i)
            #pragma unroll
            for (int r = 0; r < 4; ++r) acc[i][r] = 0.0f;

        #pragma unroll
        for (int kk = 0; kk < 8; ++kk) {
            bf16x8 a = *(const bf16x8*)&ms[m][kk * 32 + q * 8];
            #pragma unroll
            for (int i = 0; i < 4; ++i) {
                int o0 = (wid * 4 + i) * 16;
                bf16x8 b = *(const bf16x8*)(Wr_b + (size_t)(o0 + m) * 256 + kk * 32 + q * 8);
                acc[i] = __builtin_amdgcn_mfma_f32_16x16x32_bf16(a, b, acc[i], 0, 0, 0);
            }
        }
        #pragma unroll
        for (int i = 0; i < 4; ++i) {
            int o = (wid * 4 + i) * 16 + m;
            float brv = br[o];
            #pragma unroll
            for (int r = 0; r < 4; ++r) {
                int nl = q * 4 + r;
                float val = acc[i][r] + brv;
                if (degf[nl] == 0.0f) val = 0.0f;
                __builtin_nontemporal_store(val, out + (size_t)(n0 + nl) * D_OUT + o);
            }
        }
    }
}

extern "C" void kernel_launch(void* const* d_in, const int* in_sizes, int n_in,
                              void* d_out, int out_size, void* d_ws, size_t ws_size,
                              hipStream_t stream) {
    const float* x  = (const float*)d_in[0];
    const float* ez = (const float*)d_in[1];
    const int* src  = (const int*)d_in[2];
    const int* dst  = (const int*)d_in[3];
    const float* Wn = (const float*)d_in[4];
    const float* bn = (const float*)d_in[5];
    const float* We = (const float*)d_in[6];
    const float* be = (const float*)d_in[7];
    const float* Wr = (const float*)d_in[8];
    const float* br = (const float*)d_in[9];
    float* out      = (float*)d_out;

    // ---- workspace layout ----
    unsigned int* cnt      = (unsigned int*)d_ws;            // NPAD
    unsigned int* blocksum = cnt + NPAD;                     // 256
    unsigned int* blockoff = blocksum + 256;                 // 256
    unsigned int* partial  = blockoff + 256;                 // NPAD
    unsigned long long* eid_src = (unsigned long long*)(partial + NPAD); // N_EDGES u64 (8B aligned)
    unsigned short* hn = (unsigned short*)(eid_src + N_EDGES);           // N*128 bf16
    unsigned short* Wn_b = hn + (size_t)N_NODES * H;
    unsigned short* We_b = Wn_b + 32768;
    unsigned short* Wr_b = We_b + 8192;

    // zero only cnt + blocksum (the rest is fully overwritten before any read)
    hipMemsetAsync(d_ws, 0, (size_t)(NPAD + 256) * 4, stream);

    cvt_kernel<<<104, 256, 0, stream>>>(Wn, We, Wr, Wn_b, We_b, Wr_b);
    hn_kernel<<<N_NODES / 16, 64, 0, stream>>>(x, Wn_b, bn, hn);
    hist_kernel<<<N_EDGES / 256, 256, 0, stream>>>(dst, cnt);
    scan1_kernel<<<NPAD / 256, 256, 0, stream>>>(cnt, partial, blocksum);
    scan2_kernel<<<1, 256, 0, stream>>>(blocksum, blockoff);
    scatter_kernel<<<N_EDGES / 256, 256, 0, stream>>>(src, dst, partial, blockoff, eid_src);
    fused_kernel<<<N_NODES / 16, 256, 0, stream>>>(eid_src, partial, blockoff, cnt, ez,
                                                   (const unsigned int*)hn,
                                                   We_b, be, Wr_b, br, out);
}

// Round 2
// 846.379 us; speedup vs baseline: 1.0371x; 1.0310x over previous
//
#include <hip/hip_runtime.h>

#define N_NODES 50000
#define N_EDGES 1600000
#define D_NODE  256
#define D_EDGE  64
#define H       128
#define D_OUT   256

#define NPAD    50176   // 196*256, padded node count for scan

#define HN_TILES   3125           // N_NODES/16
#define HN_BLOCKS  782            // ceil(3125/4), 4 tiles (waves) per block
#define E4_BLOCKS  1563           // ceil(N_EDGES/4/256)

typedef __attribute__((ext_vector_type(8))) short bf16x8;
typedef __attribute__((ext_vector_type(4))) float f32x4;
typedef __attribute__((ext_vector_type(4))) unsigned short u16x4;
typedef __attribute__((ext_vector_type(4))) unsigned int u32x4;
typedef __attribute__((ext_vector_type(4))) int i32x4;

__device__ __forceinline__ float bf2f(unsigned short u) {
    union { unsigned int i; float f; } v; v.i = ((unsigned int)u) << 16; return v.f;
}
__device__ __forceinline__ unsigned short f2bf(float f) {
    union { float f; unsigned int i; } v; v.f = f;
    unsigned int r = v.i + 0x7FFFu + ((v.i >> 16) & 1u);
    return (unsigned short)(r >> 16);
}

// ---------- K0: convert fp32 weights to bf16 tables ----------
__global__ __launch_bounds__(256) void cvt_kernel(
        const float* __restrict__ Wn, const float* __restrict__ We,
        const float* __restrict__ Wr,
        unsigned short* __restrict__ Wn_b, unsigned short* __restrict__ We_b,
        unsigned short* __restrict__ Wr_b) {
    int b = blockIdx.x;
    const float* s; unsigned short* d; int base;
    if (b < 32)      { s = Wn; d = Wn_b; base = b * 1024; }
    else if (b < 40) { s = We; d = We_b; base = (b - 32) * 1024; }
    else             { s = Wr; d = Wr_b; base = (b - 40) * 1024; }
    int i = base + threadIdx.x * 4;
    f32x4 v = *(const f32x4*)(s + i);
    u16x4 o;
    #pragma unroll
    for (int j = 0; j < 4; ++j) o[j] = f2bf(v[j]);
    *(u16x4*)(d + i) = o;
}

// ---------- K1: fused front-end: hn GEMM (blocks < HN_BLOCKS) + dst histogram ----------
// hn = x @ Wn^T + bn -> bf16 [N,128]; hist: cnt[dst]++ (4 edges/thread).
// Independent pipes (MFMA vs atomics) overlap inside one dispatch.
__global__ __launch_bounds__(256) void front_kernel(
        const float* __restrict__ x,
        const unsigned short* __restrict__ Wn_b,
        const float* __restrict__ bn,
        unsigned short* __restrict__ hn,
        const int* __restrict__ dst,
        unsigned int* __restrict__ cnt) {
    const int b = blockIdx.x;
    if (b < HN_BLOCKS) {
        const int wid = threadIdx.x >> 6;
        const int lane = threadIdx.x & 63;
        const int tile = b * 4 + wid;
        if (tile >= HN_TILES) return;
        const int m = lane & 15, q = lane >> 4;
        const int n0 = tile * 16;

        f32x4 acc[8];
        #pragma unroll
        for (int t = 0; t < 8; ++t)
            #pragma unroll
            for (int r = 0; r < 4; ++r) acc[t][r] = 0.0f;

        const float* xrow = x + (size_t)(n0 + m) * D_NODE + q * 8;
        #pragma unroll
        for (int kk = 0; kk < 8; ++kk) {
            f32x4 a0 = __builtin_nontemporal_load((const f32x4*)(xrow + kk * 32));
            f32x4 a1 = __builtin_nontemporal_load((const f32x4*)(xrow + kk * 32 + 4));
            bf16x8 a;
            #pragma unroll
            for (int j = 0; j < 4; ++j) {
                a[j]     = (short)f2bf(a0[j]);
                a[4 + j] = (short)f2bf(a1[j]);
            }
            #pragma unroll
            for (int t = 0; t < 8; ++t) {
                bf16x8 bb = *(const bf16x8*)(Wn_b + (size_t)(t * 16 + m) * D_NODE + kk * 32 + q * 8);
                acc[t] = __builtin_amdgcn_mfma_f32_16x16x32_bf16(a, bb, acc[t], 0, 0, 0);
            }
        }
        #pragma unroll
        for (int t = 0; t < 8; ++t) {
            int o = t * 16 + m;
            float bv = bn[o];
            #pragma unroll
            for (int r = 0; r < 4; ++r) {
                int node = n0 + q * 4 + r;
                hn[(size_t)node * H + o] = f2bf(acc[t][r] + bv);
            }
        }
    } else {
        const int idx = (b - HN_BLOCKS) * 256 + threadIdx.x;
        const int e0 = idx * 4;
        if (e0 < N_EDGES) {   // N_EDGES % 4 == 0: full quad or nothing
            i32x4 d4 = *(const i32x4*)(dst + e0);
            atomicAdd(&cnt[d4[0]], 1u);
            atomicAdd(&cnt[d4[1]], 1u);
            atomicAdd(&cnt[d4[2]], 1u);
            atomicAdd(&cnt[d4[3]], 1u);
        }
    }
}

// shfl-based inclusive scan across a 256-thread block; returns inclusive, sets total.
__device__ __forceinline__ unsigned int block_scan_incl(unsigned int v, unsigned int* wtot) {
    const int lane = threadIdx.x & 63;
    const int wid = threadIdx.x >> 6;
    unsigned int x = v;
    #pragma unroll
    for (int off = 1; off < 64; off <<= 1) {
        unsigned int y = __shfl_up(x, off, 64);
        if (lane >= off) x += y;
    }
    if (lane == 63) wtot[wid] = x;
    __syncthreads();
    unsigned int wof = 0;
    #pragma unroll
    for (int w = 0; w < 4; ++w) if (w < wid) wof += wtot[w];
    return x + wof;
}

// ---------- K2b: per-block scan ----------
__global__ __launch_bounds__(256) void scan1_kernel(
        const unsigned int* __restrict__ cnt,
        unsigned int* __restrict__ partial,   // exclusive within block
        unsigned int* __restrict__ blocksum) {
    __shared__ unsigned int wtot[4];
    int i = blockIdx.x * 256 + threadIdx.x;
    unsigned int v = cnt[i];
    unsigned int inc = block_scan_incl(v, wtot);
    partial[i] = inc - v;
    if (threadIdx.x == 255) blocksum[blockIdx.x] = inc;
}

// ---------- K2c: scan the 196 block sums (padded to 256) ----------
__global__ __launch_bounds__(256) void scan2_kernel(
        const unsigned int* __restrict__ blocksum,
        unsigned int* __restrict__ blockoff) {
    __shared__ unsigned int wtot[4];
    unsigned int v = blocksum[threadIdx.x];
    unsigned int inc = block_scan_incl(v, wtot);
    blockoff[threadIdx.x] = inc - v;   // exclusive
}

// ---------- K2d: scatter edge ids into dst-bins (4 edges/thread) ----------
// atomics run directly on partial[]; global position = partial-atomic + blockoff.
// After this kernel partial[n] == within-block-exclusive + cnt[n].
__global__ __launch_bounds__(256) void scatter_kernel(
        const int* __restrict__ src, const int* __restrict__ dst,
        unsigned int* __restrict__ partial,
        const unsigned int* __restrict__ blockoff,
        unsigned long long* __restrict__ eid_src) {
    const int idx = blockIdx.x * 256 + threadIdx.x;
    const int e0 = idx * 4;
    if (e0 >= N_EDGES) return;
    i32x4 s4 = *(const i32x4*)(src + e0);
    i32x4 d4 = *(const i32x4*)(dst + e0);
    #pragma unroll
    for (int k = 0; k < 4; ++k) {
        int d = d4[k];
        unsigned int pos = atomicAdd(&partial[d], 1u) + blockoff[d >> 8];
        eid_src[pos] = ((unsigned long long)(unsigned int)s4[k] << 32) | (unsigned int)(e0 + k);
    }
}

// ---------- K3: fused aggregation + mean_state + out GEMM, 16 nodes/block ----------
// Aggregation: each 16-lane group owns one edge row per load instruction
// (f32x4/u32x4 = 16 B/lane -> 4 edges per wave-instruction, 4x fewer VMEM issues).
__global__ __launch_bounds__(256) void fused_kernel(
        const unsigned long long* __restrict__ eid_src,
        const unsigned int* __restrict__ partial,   // post-scatter
        const unsigned int* __restrict__ blockoff,
        const unsigned int* __restrict__ cnt,
        const float* __restrict__ ez,
        const unsigned int* __restrict__ hn32,
        const unsigned short* __restrict__ We_b,
        const float* __restrict__ be,
        const unsigned short* __restrict__ Wr_b,
        const float* __restrict__ br,
        float* __restrict__ out) {
    __shared__ __align__(16) unsigned short ms[16][264];
    __shared__ __align__(16) float seL[16][68];
    __shared__ float rden[16];
    __shared__ float degf[16];

    const int t = threadIdx.x;
    const int n0 = blockIdx.x * 16;
    const int wid = t >> 6;
    const int lane = t & 63;
    const int q = lane >> 4;       // edge slot within a 4-edge group
    const int l16 = lane & 15;     // column-quad owner within a row

    if (t < 16) {
        unsigned int dg = cnt[n0 + t];
        degf[t] = (float)dg;
        rden[t] = 1.0f / (1.0f + (float)dg);
    }

    // ---- phase 1: aggregation. wave wid owns nodes wid*4 .. wid*4+3 ----
    for (int nl = 0; nl < 4; ++nl) {
        const int row = wid * 4 + nl;
        const int n = n0 + row;
        const unsigned int c = cnt[n];
        const unsigned int end = partial[n] + blockoff[n >> 8];
        const unsigned int beg = end - c;

        f32x4 sez; sez[0] = sez[1] = sez[2] = sez[3] = 0.0f;
        float snlo[4] = {0.f, 0.f, 0.f, 0.f};   // bf16 cols 2*(l16*4+k)
        float snhi[4] = {0.f, 0.f, 0.f, 0.f};   // bf16 cols 2*(l16*4+k)+1

        for (unsigned int base = beg; base < end; base += 64) {
            int mcnt = (int)(end - base); if (mcnt > 64) mcnt = 64;
            unsigned long long ent = (lane < mcnt)
                ? __builtin_nontemporal_load(eid_src + base + lane) : 0ULL;
            unsigned int elo = (unsigned int)ent;
            unsigned int shi = (unsigned int)(ent >> 32);

            int j = 0;
            for (; j + 8 <= mcnt; j += 8) {
                unsigned int e0 = __shfl(elo, j + q, 64);
                unsigned int s0 = __shfl(shi, j + q, 64);
                unsigned int e1 = __shfl(elo, j + 4 + q, 64);
                unsigned int s1 = __shfl(shi, j + 4 + q, 64);
                f32x4 a0 = __builtin_nontemporal_load((const f32x4*)(ez + (size_t)e0 * D_EDGE + l16 * 4));
                f32x4 a1 = __builtin_nontemporal_load((const f32x4*)(ez + (size_t)e1 * D_EDGE + l16 * 4));
                u32x4 h0 = *(const u32x4*)(hn32 + (size_t)s0 * 64 + l16 * 4);
                u32x4 h1 = *(const u32x4*)(hn32 + (size_t)s1 * 64 + l16 * 4);
                sez += a0; sez += a1;
                #pragma unroll
                for (int k = 0; k < 4; ++k) {
                    union { unsigned int ui; float f; } lo, hi;
                    lo.ui = h0[k] << 16; hi.ui = h0[k] & 0xffff0000u;
                    snlo[k] += lo.f; snhi[k] += hi.f;
                    lo.ui = h1[k] << 16; hi.ui = h1[k] & 0xffff0000u;
                    snlo[k] += lo.f; snhi[k] += hi.f;
                }
            }
            for (; j < mcnt; j += 4) {
                int i0 = j + q;
                unsigned int e0 = __shfl(elo, i0, 64);
                unsigned int s0 = __shfl(shi, i0, 64);
                if (i0 < mcnt) {
                    f32x4 a0 = __builtin_nontemporal_load((const f32x4*)(ez + (size_t)e0 * D_EDGE + l16 * 4));
                    u32x4 h0 = *(const u32x4*)(hn32 + (size_t)s0 * 64 + l16 * 4);
                    sez += a0;
                    #pragma unroll
                    for (int k = 0; k < 4; ++k) {
                        union { unsigned int ui; float f; } lo, hi;
                        lo.ui = h0[k] << 16; hi.ui = h0[k] & 0xffff0000u;
                        snlo[k] += lo.f; snhi[k] += hi.f;
                    }
                }
            }
        }

        // reduce the 4 edge-slot groups (lanes l16, l16+16, l16+32, l16+48)
        #pragma unroll
        for (int k = 0; k < 4; ++k) {
            sez[k]  += __shfl_xor(sez[k], 16, 64);
            sez[k]  += __shfl_xor(sez[k], 32, 64);
            snlo[k] += __shfl_xor(snlo[k], 16, 64);
            snlo[k] += __shfl_xor(snlo[k], 32, 64);
            snhi[k] += __shfl_xor(snhi[k], 16, 64);
            snhi[k] += __shfl_xor(snhi[k], 32, 64);
        }

        if (q == 0) {
            float rd = 1.0f / (1.0f + (float)c);
            *(f32x4*)&seL[row][l16 * 4] = sez;
            // node half: ms[row, :128] = (hn[n] + sumN) / (deg+1)
            u32x4 hv = *(const u32x4*)(hn32 + (size_t)n * 64 + l16 * 4);
            u32x4 pk;
            #pragma unroll
            for (int k = 0; k < 4; ++k) {
                union { unsigned int ui; float f; } lo, hi;
                lo.ui = hv[k] << 16; hi.ui = hv[k] & 0xffff0000u;
                pk[k] = ((unsigned int)f2bf((hi.f + snhi[k]) * rd) << 16)
                      |  (unsigned int)f2bf((lo.f + snlo[k]) * rd);
            }
            *(u32x4*)&ms[row][l16 * 8] = pk;
        }
    }
    __syncthreads();

    // ---- phase 2: edge half: ms[:,128:256] = (sumEZ @ We^T + deg*be) * rden ----
    {
        const int m = lane & 15, qq = lane >> 4;
        f32x4 acc[2];
        #pragma unroll
        for (int i = 0; i < 2; ++i)
            #pragma unroll
            for (int r = 0; r < 4; ++r) acc[i][r] = 0.0f;

        #pragma unroll
        for (int kk = 0; kk < 2; ++kk) {
            const float* ap = &seL[m][kk * 32 + qq * 8];
            f32x4 a0 = *(const f32x4*)ap;
            f32x4 a1 = *(const f32x4*)(ap + 4);
            bf16x8 a;
            #pragma unroll
            for (int j = 0; j < 4; ++j) {
                a[j]     = (short)f2bf(a0[j]);
                a[4 + j] = (short)f2bf(a1[j]);
            }
            #pragma unroll
            for (int i = 0; i < 2; ++i) {
                int o0 = (wid + 4 * i) * 16;
                bf16x8 b = *(const bf16x8*)(We_b + (size_t)(o0 + m) * D_EDGE + kk * 32 + qq * 8);
                acc[i] = __builtin_amdgcn_mfma_f32_16x16x32_bf16(a, b, acc[i], 0, 0, 0);
            }
        }
        #pragma unroll
        for (int i = 0; i < 2; ++i) {
            int o = (wid + 4 * i) * 16 + m;
            float bev = be[o];
            #pragma unroll
            for (int r = 0; r < 4; ++r) {
                int nl = qq * 4 + r;
                float val = (acc[i][r] + degf[nl] * bev) * rden[nl];
                ms[nl][128 + o] = f2bf(val);
            }
        }
    }
    __syncthreads();

    // ---- phase 3: out = ms @ Wr^T + br ; zero rows with deg==0 ----
    {
        const int m = lane & 15, qq = lane >> 4;
        f32x4 acc[4];
        #pragma unroll
        for (int i = 0; i < 4; ++i)
            #pragma unroll
            for (int r = 0; r < 4; ++r) acc[i][r] = 0.0f;

        #pragma unroll
        for (int kk = 0; kk < 8; ++kk) {
            bf16x8 a = *(const bf16x8*)&ms[m][kk * 32 + qq * 8];
            #pragma unroll
            for (int i = 0; i < 4; ++i) {
                int o0 = (wid * 4 + i) * 16;
                bf16x8 b = *(const bf16x8*)(Wr_b + (size_t)(o0 + m) * 256 + kk * 32 + qq * 8);
                acc[i] = __builtin_amdgcn_mfma_f32_16x16x32_bf16(a, b, acc[i], 0, 0, 0);
            }
        }
        #pragma unroll
        for (int i = 0; i < 4; ++i) {
            int o = (wid * 4 + i) * 16 + m;
            float brv = br[o];
            #pragma unroll
            for (int r = 0; r < 4; ++r) {
                int nl = qq * 4 + r;
                float val = acc[i][r] + brv;
                if (degf[nl] == 0.0f) val = 0.0f;
                __builtin_nontemporal_store(val, out + (size_t)(n0 + nl) * D_OUT + o);
            }
        }
    }
}

extern "C" void kernel_launch(void* const* d_in, const int* in_sizes, int n_in,
                              void* d_out, int out_size, void* d_ws, size_t ws_size,
                              hipStream_t stream) {
    const float* x  = (const float*)d_in[0];
    const float* ez = (const float*)d_in[1];
    const int* src  = (const int*)d_in[2];
    const int* dst  = (const int*)d_in[3];
    const float* Wn = (const float*)d_in[4];
    const float* bn = (const float*)d_in[5];
    const float* We = (const float*)d_in[6];
    const float* be = (const float*)d_in[7];
    const float* Wr = (const float*)d_in[8];
    const float* br = (const float*)d_in[9];
    float* out      = (float*)d_out;

    // ---- workspace layout ----
    unsigned int* cnt      = (unsigned int*)d_ws;            // NPAD
    unsigned int* blocksum = cnt + NPAD;                     // 256
    unsigned int* blockoff = blocksum + 256;                 // 256
    unsigned int* partial  = blockoff + 256;                 // NPAD
    unsigned long long* eid_src = (unsigned long long*)(partial + NPAD); // N_EDGES u64 (8B aligned)
    unsigned short* hn = (unsigned short*)(eid_src + N_EDGES);           // N*128 bf16
    unsigned short* Wn_b = hn + (size_t)N_NODES * H;
    unsigned short* We_b = Wn_b + 32768;
    unsigned short* Wr_b = We_b + 8192;

    // zero only cnt + blocksum (the rest is fully overwritten before any read)
    hipMemsetAsync(d_ws, 0, (size_t)(NPAD + 256) * 4, stream);

    cvt_kernel<<<104, 256, 0, stream>>>(Wn, We, Wr, Wn_b, We_b, Wr_b);
    front_kernel<<<HN_BLOCKS + E4_BLOCKS, 256, 0, stream>>>(x, Wn_b, bn, hn, dst, cnt);
    scan1_kernel<<<NPAD / 256, 256, 0, stream>>>(cnt, partial, blocksum);
    scan2_kernel<<<1, 256, 0, stream>>>(blocksum, blockoff);
    scatter_kernel<<<E4_BLOCKS, 256, 0, stream>>>(src, dst, partial, blockoff, eid_src);
    fused_kernel<<<N_NODES / 16, 256, 0, stream>>>(eid_src, partial, blockoff, cnt, ez,
                                                   (const unsigned int*)hn,
                                                   We_b, be, Wr_b, br, out);
}